// Round 3
// baseline (1024.340 us; speedup 1.0000x reference)
//
#include <hip/hip_runtime.h>
#include <hip/hip_fp16.h>

typedef _Float16 v8h __attribute__((ext_vector_type(8)));
typedef _Float16 v4h __attribute__((ext_vector_type(4)));
typedef float v4f __attribute__((ext_vector_type(4)));

#define T_DIM 512
#define B_DIM 256
#define F_DIM 258
#define IN_DIM 256
#define H_DIM 1024
#define M_ROWS (T_DIM * B_DIM) /* 131072 */

// XCD-aware tile map: blocks on one XCD share an m-panel across all nt
// (consecutive blocks on an XCD iterate nt fastest -> B tile fetched from
// HBM once, 3 L2 hits; weights L2-resident anyway)
__device__ __forceinline__ void tile_map(int b, int nM, int nN, int& mt, int& nt) {
    if ((nM & 7) == 0) {
        int xcd = b & 7;
        int l = b >> 3;
        int mpx = nM >> 3;
        int lm = l / nN;
        mt = xcd * mpx + lm;
        nt = l - lm * nN;
    } else {
        int lm = b / nN;
        mt = lm;
        nt = b - lm * nN;
    }
}

// async global->LDS, 16B per lane, lane-linear LDS destination
__device__ __forceinline__ void gl16(const _Float16* g, _Float16* l) {
    __builtin_amdgcn_global_load_lds(
        (const __attribute__((address_space(1))) unsigned int*)g,
        (__attribute__((address_space(3))) unsigned int*)l, 16, 0, 0);
}

// ---------------------------------------------------------------------------
// Activations live in blocked "bk8" layout: X[m][k] at
//   ((m>>4)*(K>>3) + (k>>3))*128 + (m&15)*8 + (k&7)
// -> any B-fragment is one coalesced 16B/lane load; ds_read_b128 of a
//    fragment is a contiguous 1KB wave sweep: zero bank conflicts, and
//    global_load_lds's lane-linear LDS dest maps 1:1 onto the layout.
// Weights are fragment-major and read REGISTER-DIRECT from L1/L2 (A port),
// so LDS carries only B traffic: two delivery ports instead of one.
// ---------------------------------------------------------------------------

// prep: u (Mc,258) fp32 -> X bk8 fp16 + c1 seg
__global__ void prep_u_kernel(const float* __restrict__ u,
                              _Float16* __restrict__ X,
                              float* __restrict__ c1, int n) {
    int i = blockIdx.x * blockDim.x + threadIdx.x;
    int stride = gridDim.x * blockDim.x;
    for (; i < n; i += stride) {
        float v = u[i];
        unsigned r = (unsigned)i / 258u;
        unsigned c = (unsigned)i - r * 258u;
        if (c >= 2u) {
            unsigned k = c - 2u;
            X[((r >> 4) * 32u + (k >> 3)) * 128u + (r & 15u) * 8u + (k & 7u)] =
                (_Float16)v;
        } else if (c == 1u) {
            c1[r] = v;
        }
    }
}

// ---------------------------------------------------------------------------
// weight -> fragment-major fp16. W (K x N fp32).
// Frag f=(g*KC+kc)*4+i holds n = g*64+i*16+(l&15), k = kc*32+(l>>4)*8+j.
// ---------------------------------------------------------------------------
__global__ void wt_frag_kernel(const float* __restrict__ W,
                               _Float16* __restrict__ BF, int K, int N) {
    int idx = blockIdx.x * blockDim.x + threadIdx.x;
    int total = (N >> 6) * (K >> 5) * 4 * 64;
    if (idx >= total) return;
    int l = idx & 63;
    int f = idx >> 6;
    int i = f & 3;
    int gk = f >> 2;
    int KC = K >> 5;
    int g = gk / KC, kc = gk - g * KC;
    int col = g * 64 + i * 16 + (l & 15);
    int krow = kc * 32 + (l >> 4) * 8;
    _Float16 tmp[8];
#pragma unroll
    for (int j = 0; j < 8; ++j) tmp[j] = (_Float16)W[(size_t)(krow + j) * N + col];
    *(v8h*)&BF[(size_t)idx * 8] = *(v8h*)tmp;
}

__global__ void wt_vec_kernel(const float* __restrict__ W,
                              _Float16* __restrict__ Wh, int K) {
    int i = blockIdx.x * blockDim.x + threadIdx.x;
    if (i < K) Wh[i] = (_Float16)W[i];
}

__global__ void zero_kernel(float* __restrict__ p, int n) {
    int i = blockIdx.x * blockDim.x + threadIdx.x;
    if (i < n) p[i] = 0.f;
}

// ---------------------------------------------------------------------------
// 256x256 GEMM, 8 waves (2M x 4N), BK=64. B (activations) double-buffered in
// 64KB LDS via global_load_lds; A (weights) register-direct from L1/L2
// (frag-major contiguous 16B/lane loads, SIMD-mate's re-read hits L1).
// One barrier per K-tile (buffer swap). B-fragments register-double-buffered
// one phase ahead so ds_reads issue under the previous phase's MFMAs.
// ---------------------------------------------------------------------------
template <int MI0>
__device__ __forceinline__ void mfma_pair(v4f (&acc)[8][4], const v8h (&af)[4][2],
                                          const v8h (&b)[4]) {
#pragma unroll
    for (int ni = 0; ni < 4; ++ni) {
        acc[MI0][ni] = __builtin_amdgcn_mfma_f32_16x16x32_f16(
            af[ni][0], b[0], acc[MI0][ni], 0, 0, 0);
        acc[MI0][ni] = __builtin_amdgcn_mfma_f32_16x16x32_f16(
            af[ni][1], b[1], acc[MI0][ni], 0, 0, 0);
        acc[MI0 + 1][ni] = __builtin_amdgcn_mfma_f32_16x16x32_f16(
            af[ni][0], b[2], acc[MI0 + 1][ni], 0, 0, 0);
        acc[MI0 + 1][ni] = __builtin_amdgcn_mfma_f32_16x16x32_f16(
            af[ni][1], b[3], acc[MI0 + 1][ni], 0, 0, 0);
    }
}

template <int DOT>
__global__ __launch_bounds__(512, 2)
void gemm256(const _Float16* __restrict__ Xb, const _Float16* __restrict__ WF,
             const float* __restrict__ bias, const _Float16* __restrict__ w3,
             _Float16* __restrict__ Cb, float* __restrict__ net,
             int M, int N, int K) {
    extern __shared__ _Float16 lds[];  // 2 x 16384 elems (B double buffer)
    const int tid = threadIdx.x;
    const int lane = tid & 63;
    const int wave = tid >> 6;
    const int wm = wave >> 2;  // 0..1 (128 m-rows each)
    const int wn = wave & 3;   // 0..3 (64 n-cols each)
    const int quad = lane >> 4;
    const int r16 = lane & 15;
    const int wm8 = wm * 8;
    const int lrb = lane * 8;  // B-frag lane offset (elts), fully linear

    int mt, nt;
    tile_map(blockIdx.x, M >> 8, N >> 8, mt, nt);
    const int m0 = mt * 256;
    const int n0 = nt * 256;

    const int KC = K >> 5;   // 32-k chunks per weight group
    const int KC8 = K >> 3;  // 8-k blocks per activation m-block row
    const int NT = K >> 6;   // number of 64-k tiles
    const int m016 = m0 >> 4;
    const int nt4 = nt * 4;

    // one stage op = 512 threads x 16B = 8KB, lane-linear into LDS
    auto stageB = [&](int mb, int kt, _Float16* pb) {
        gl16(Xb + ((size_t)(m016 + mb + (tid >> 7)) * KC8 + (size_t)kt * 8) * 128 +
                 (tid & 127) * 8,
             pb + mb * 1024 + tid * 8);
    };
    // 4 B-frags (one mi-pair): contiguous 1KB wave sweeps
    auto loadB = [&](const _Float16* pB, int mb, v8h (&b)[4]) {
        b[0] = *(const v8h*)(pB + mb * 1024 + lrb);
        b[1] = *(const v8h*)(pB + mb * 1024 + 512 + lrb);
        b[2] = *(const v8h*)(pB + (mb + 1) * 1024 + lrb);
        b[3] = *(const v8h*)(pB + (mb + 1) * 1024 + 512 + lrb);
    };

    // A-operand base for this wave's 64-col group (register-direct reads)
    const _Float16* wp0 = WF + (size_t)(nt4 + wn) * KC * 2048 + lane * 8;

    v4f acc[8][4];
#pragma unroll
    for (int i = 0; i < 8; ++i)
#pragma unroll
        for (int j = 0; j < 4; ++j) acc[i][j] = (v4f)0.f;

    // ---- prologue: stage B tile 0 into buf0, wait, one barrier ----
    {
        stageB(0, 0, lds); stageB(4, 0, lds);
        stageB(8, 0, lds); stageB(12, 0, lds);
        asm volatile("s_waitcnt vmcnt(0)" ::: "memory");
        __builtin_amdgcn_s_barrier();
    }

#pragma unroll 2
    for (int kt = 0; kt < NT; ++kt) {
        _Float16* pBc = lds + (kt & 1) * 16384;
        _Float16* pBn = lds + ((kt + 1) & 1) * 16384;
        const bool pre = (kt + 1 < NT);
        const int kn = kt + 1;

        // ---- A-frags: register-direct global loads (L1/L2), issued first ----
        const _Float16* wpt = wp0 + (size_t)kt * 4096;
        v8h af[4][2];
#pragma unroll
        for (int i = 0; i < 4; ++i) {
            af[i][0] = *(const v8h*)(wpt + i * 512);
            af[i][1] = *(const v8h*)(wpt + 2048 + i * 512);
        }
        v8h bA[4], bB[4];
        loadB(pBc, wm8 + 0, bA);

        // ---- issue next-tile B staging (lands in other buffer, async) ----
        if (pre) {
            stageB(0, kn, pBn); stageB(4, kn, pBn);
            stageB(8, kn, pBn); stageB(12, kn, pBn);
        }

        // ---- self-paced phases, B regs double-buffered one phase ahead ----
        loadB(pBc, wm8 + 2, bB);
        __builtin_amdgcn_s_setprio(1);
        mfma_pair<0>(acc, af, bA);
        __builtin_amdgcn_s_setprio(0);

        loadB(pBc, wm8 + 4, bA);
        __builtin_amdgcn_s_setprio(1);
        mfma_pair<2>(acc, af, bB);
        __builtin_amdgcn_s_setprio(0);

        loadB(pBc, wm8 + 6, bB);
        __builtin_amdgcn_s_setprio(1);
        mfma_pair<4>(acc, af, bA);
        __builtin_amdgcn_s_setprio(0);

        __builtin_amdgcn_s_setprio(1);
        mfma_pair<6>(acc, af, bB);
        __builtin_amdgcn_s_setprio(0);

        // ---- tile boundary: the ONLY sync per K-tile ----
        if (kt != NT - 1) {
            // own LDS reads of buf[cur] done (free: consumed by MFMAs above)
            asm volatile("s_waitcnt lgkmcnt(0)" ::: "memory");
            // own B-DMA share of tile t+1 done (af loads long since returned)
            asm volatile("s_waitcnt vmcnt(0)" ::: "memory");
            // all waves: buf[cur^1] fully written, buf[cur] free for t+2 DMA
            __builtin_amdgcn_s_barrier();
        }
    }

    // ---- epilogue: lane holds n = nb+ni*16+quad*4+i, m = mb+mi*16+r16 ----
    const int nb = n0 + wn * 64;
    v4f bv[4];
#pragma unroll
    for (int ni = 0; ni < 4; ++ni)
        bv[ni] = *(const v4f*)&bias[nb + ni * 16 + quad * 4];

    if constexpr (DOT == 0) {
        const int NC8 = N >> 3;
#pragma unroll
        for (int ni = 0; ni < 4; ++ni) {
            const int nblk = ((nb + ni * 16) >> 3) + (quad >> 1);
#pragma unroll
            for (int mi = 0; mi < 8; ++mi) {
                v4h hv;
#pragma unroll
                for (int i = 0; i < 4; ++i)
                    hv[i] = (_Float16)fmaxf(acc[mi][ni][i] + bv[ni][i], 0.f);
                const size_t mblk = (size_t)((m0 + wm * 128 + mi * 16) >> 4);
                _Float16* dst =
                    Cb + (mblk * NC8 + nblk) * 128 + r16 * 8 + (quad & 1) * 4;
                *(v4h*)dst = hv;
            }
        }
    } else {
        v4h wv[4];
#pragma unroll
        for (int ni = 0; ni < 4; ++ni)
            wv[ni] = *(const v4h*)&w3[nb + ni * 16 + quad * 4];
#pragma unroll
        for (int mi = 0; mi < 8; ++mi) {
            float t = 0.f;
#pragma unroll
            for (int ni = 0; ni < 4; ++ni)
#pragma unroll
                for (int i = 0; i < 4; ++i) {
                    float v = fmaxf(acc[mi][ni][i] + bv[ni][i], 0.f);
                    t = fmaf(v, (float)wv[ni][i], t);
                }
            t += __shfl_xor(t, 16);
            t += __shfl_xor(t, 32);
            if (quad == 0) {
                int row = m0 + wm * 128 + mi * 16 + r16;
                atomicAdd(&net[row], t);
            }
        }
    }
}

// ---------------------------------------------------------------------------
// scan: y_t = a*y_{t-1} + b*c1_t + (net_t + b3) ; out = [y0; ys]
// ---------------------------------------------------------------------------
__global__ void scan_kernel(const float* __restrict__ net,
                            const float* __restrict__ c1,
                            const float* __restrict__ u,
                            const float* __restrict__ pa,
                            const float* __restrict__ pb,
                            const float* __restrict__ pb3,
                            float* __restrict__ out) {
    const int bidx = threadIdx.x;  // 0..255
    const float a = pa[0];
    const float b = pb[0];
    const float b3 = pb3[0];
    float y = u[(size_t)bidx * F_DIM];  // u[0, b, 0]
    out[bidx] = y;
#pragma unroll 8
    for (int t = 0; t < T_DIM; ++t) {
        float z = fmaf(b, c1[t * B_DIM + bidx], net[t * B_DIM + bidx] + b3);
        y = fmaf(a, y, z);
        out[(t + 1) * B_DIM + bidx] = y;
    }
}

// ---------------------------------------------------------------------------
extern "C" void kernel_launch(void* const* d_in, const int* in_sizes, int n_in,
                              void* d_out, int out_size, void* d_ws, size_t ws_size,
                              hipStream_t stream) {
    const float* u = (const float*)d_in[0];
    const float* pa = (const float*)d_in[1];
    const float* pb = (const float*)d_in[2];
    const float* W0 = (const float*)d_in[3];
    const float* b0 = (const float*)d_in[4];
    const float* W1 = (const float*)d_in[5];
    const float* b1 = (const float*)d_in[6];
    const float* W2 = (const float*)d_in[7];
    const float* b2 = (const float*)d_in[8];
    const float* W3 = (const float*)d_in[9];
    const float* b3 = (const float*)d_in[10];
    float* out = (float*)d_out;

    char* ws = (char*)d_ws;
    size_t off = 0;
    auto alloc = [&](size_t bytes) -> void* {
        void* p = ws + off;
        off += (bytes + 255) & ~(size_t)255;
        return p;
    };

    // ---- fixed residents (~5.8 MB) ----
    float* net = (float*)alloc((size_t)M_ROWS * 4);
    float* c1 = (float*)alloc((size_t)M_ROWS * 4);
    _Float16* W0F = (_Float16*)alloc((size_t)IN_DIM * H_DIM * 2);
    _Float16* W1F = (_Float16*)alloc((size_t)H_DIM * H_DIM * 2);
    _Float16* W2F = (_Float16*)alloc((size_t)H_DIM * H_DIM * 2);
    _Float16* W3h = (_Float16*)alloc((size_t)H_DIM * 2);

    // ---- chunk rows: multiple of 2048 (256-tile + XCD swizzle path) ----
    const size_t per_row = 512 + 2048 + 2048;
    size_t avail = (ws_size > off + 65536) ? (ws_size - off - 65536) : 0;
    long Rl = (long)(avail / per_row);
    Rl = (Rl / 2048) * 2048;
    if (Rl < 2048) Rl = 2048;
    if (Rl > M_ROWS) Rl = M_ROWS;
    const int R = (int)Rl;

    _Float16* Xc = (_Float16*)alloc((size_t)R * IN_DIM * 2);
    _Float16* HAc = (_Float16*)alloc((size_t)R * H_DIM * 2);
    _Float16* HBc = (_Float16*)alloc((size_t)R * H_DIM * 2);

    // ---- weights once per call (fragment-major) ----
    wt_frag_kernel<<<(IN_DIM / 32) * (H_DIM / 64), 256, 0, stream>>>(W0, W0F,
                                                                     IN_DIM, H_DIM);
    wt_frag_kernel<<<(H_DIM / 32) * (H_DIM / 64), 256, 0, stream>>>(W1, W1F,
                                                                    H_DIM, H_DIM);
    wt_frag_kernel<<<(H_DIM / 32) * (H_DIM / 64), 256, 0, stream>>>(W2, W2F,
                                                                    H_DIM, H_DIM);
    wt_vec_kernel<<<4, 256, 0, stream>>>(W3, W3h, H_DIM);
    zero_kernel<<<M_ROWS / 256, 256, 0, stream>>>(net, M_ROWS);

    // ---- chunked MLP pipeline ----
    const size_t lds_bytes = 65536;  // 2 x 32KB B buffers (A is reg-direct)
    for (int r0 = 0; r0 < M_ROWS; r0 += R) {
        int Mc = M_ROWS - r0;
        if (Mc > R) Mc = R;
        int nElem = Mc * F_DIM;
        int pgrid = (nElem + 256 * 8 - 1) / (256 * 8);
        if (pgrid > 2048) pgrid = 2048;
        prep_u_kernel<<<pgrid, 256, 0, stream>>>(u + (size_t)r0 * F_DIM, Xc,
                                                 c1 + r0, nElem);

        dim3 blk(512);
        dim3 grd((Mc / 256) * (H_DIM / 256));  // 1D, swizzled in-kernel
        gemm256<0><<<grd, blk, lds_bytes, stream>>>(Xc, W0F, b0, nullptr, HAc,
                                                    nullptr, Mc, H_DIM, IN_DIM);
        gemm256<0><<<grd, blk, lds_bytes, stream>>>(HAc, W1F, b1, nullptr, HBc,
                                                    nullptr, Mc, H_DIM, H_DIM);
        gemm256<1><<<grd, blk, lds_bytes, stream>>>(HBc, W2F, b2, W3h, nullptr,
                                                    net + r0, Mc, H_DIM, H_DIM);
    }

    // ---- scan ----
    scan_kernel<<<1, 256, 0, stream>>>(net, c1, u, pa, pb, b3, out);
}

// Round 4
// 926.549 us; speedup vs baseline: 1.1055x; 1.1055x over previous
//
#include <hip/hip_runtime.h>
#include <hip/hip_fp16.h>

typedef _Float16 v8h __attribute__((ext_vector_type(8)));
typedef _Float16 v4h __attribute__((ext_vector_type(4)));
typedef float v4f __attribute__((ext_vector_type(4)));

#define T_DIM 512
#define B_DIM 256
#define F_DIM 258
#define IN_DIM 256
#define H_DIM 1024
#define M_ROWS (T_DIM * B_DIM) /* 131072 */

// XCD-aware tile map: blocks on one XCD share an m-panel across all nt
__device__ __forceinline__ void tile_map(int b, int nM, int nN, int& mt, int& nt) {
    if ((nM & 7) == 0) {
        int xcd = b & 7;
        int l = b >> 3;
        int mpx = nM >> 3;
        int lm = l / nN;
        mt = xcd * mpx + lm;
        nt = l - lm * nN;
    } else {
        int lm = b / nN;
        mt = lm;
        nt = b - lm * nN;
    }
}

// async global->LDS, 16B per lane, lane-linear LDS destination
__device__ __forceinline__ void gl16(const _Float16* g, _Float16* l) {
    __builtin_amdgcn_global_load_lds(
        (const __attribute__((address_space(1))) unsigned int*)g,
        (__attribute__((address_space(3))) unsigned int*)l, 16, 0, 0);
}

// ---------------------------------------------------------------------------
// Activations live in blocked "bk8" layout: X[m][k] at
//   ((m>>4)*(K>>3) + (k>>3))*128 + (m&15)*8 + (k&7)
// -> any B-fragment is one coalesced 16B/lane load; ds_read_b128 of a
//    fragment is a contiguous 1KB wave sweep: zero bank conflicts, and
//    global_load_lds's lane-linear LDS dest maps 1:1 onto the layout.
// ---------------------------------------------------------------------------

// prep: u (Mc,258) fp32 -> X bk8 fp16, vectorized (v8h stores, linear in X)
// thread i -> r = (i>>9)*16 + (i&15), kb = (i>>4)&31; writes X 16B at
// ((r>>4)*32 + kb)*128 + (r&15)*8 : consecutive i = consecutive 16B -> linear.
__global__ void prep_x_kernel(const float* __restrict__ u,
                              _Float16* __restrict__ X, int nrows) {
    int i = blockIdx.x * blockDim.x + threadIdx.x;
    int total = nrows * 32;
    int stride = gridDim.x * blockDim.x;
    for (; i < total; i += stride) {
        int r = ((i >> 9) << 4) + (i & 15);
        int kb = (i >> 4) & 31;
        const float* s = u + (size_t)r * 258 + 2 + kb * 8;
        _Float16 h[8];
#pragma unroll
        for (int j = 0; j < 8; ++j) h[j] = (_Float16)s[j];
        *(v8h*)(X + ((size_t)(r >> 4) * 32 + kb) * 128 + (r & 15) * 8) =
            *(v8h*)h;
    }
}

__global__ void prep_c1_kernel(const float* __restrict__ u,
                               float* __restrict__ c1, int nrows) {
    int r = blockIdx.x * blockDim.x + threadIdx.x;
    if (r < nrows) c1[r] = u[(size_t)r * 258 + 1];
}

// ---------------------------------------------------------------------------
// weight -> fragment-major fp16. W (K x N fp32).
// Frag f=(g*KC+kc)*4+i holds n = g*64+i*16+(l&15), k = kc*32+(l>>4)*8+j.
// ---------------------------------------------------------------------------
__global__ void wt_frag_kernel(const float* __restrict__ W,
                               _Float16* __restrict__ BF, int K, int N) {
    int idx = blockIdx.x * blockDim.x + threadIdx.x;
    int total = (N >> 6) * (K >> 5) * 4 * 64;
    if (idx >= total) return;
    int l = idx & 63;
    int f = idx >> 6;
    int i = f & 3;
    int gk = f >> 2;
    int KC = K >> 5;
    int g = gk / KC, kc = gk - g * KC;
    int col = g * 64 + i * 16 + (l & 15);
    int krow = kc * 32 + (l >> 4) * 8;
    _Float16 tmp[8];
#pragma unroll
    for (int j = 0; j < 8; ++j) tmp[j] = (_Float16)W[(size_t)(krow + j) * N + col];
    *(v8h*)&BF[(size_t)idx * 8] = *(v8h*)tmp;
}

__global__ void wt_vec_kernel(const float* __restrict__ W,
                              _Float16* __restrict__ Wh, int K) {
    int i = blockIdx.x * blockDim.x + threadIdx.x;
    if (i < K) Wh[i] = (_Float16)W[i];
}

__global__ void zero_kernel(float* __restrict__ p, int n) {
    int i = blockIdx.x * blockDim.x + threadIdx.x;
    if (i < n) p[i] = 0.f;
}

// ---------------------------------------------------------------------------
// 256x128 GEMM block, 4 waves (2M x 2N), wave tile 128x64, BK=32.
// 48KB LDS double buffer -> 2 blocks/CU resident: block B's MFMA bursts
// cover block A's read bursts / boundary drains / epilogue (the measured
// ~12% no-block bubbles + burst serialization at 1 block/CU).
// One barrier per K-tile; DMA for t+1 targets the other buffer.
// ---------------------------------------------------------------------------
template <int MI0>
__device__ __forceinline__ void mfma16(v4f (&acc)[8][4], const v8h (&af)[4],
                                       const v8h (&b)[4]) {
#pragma unroll
    for (int mi = 0; mi < 4; ++mi)
#pragma unroll
        for (int ni = 0; ni < 4; ++ni)
            acc[MI0 + mi][ni] = __builtin_amdgcn_mfma_f32_16x16x32_f16(
                af[ni], b[mi], acc[MI0 + mi][ni], 0, 0, 0);
}

template <int DOT>
__global__ __launch_bounds__(256, 2)
void gemm256(const _Float16* __restrict__ Xb, const _Float16* __restrict__ WF,
             const float* __restrict__ bias, const _Float16* __restrict__ w3,
             _Float16* __restrict__ Cb, float* __restrict__ net,
             int M, int N, int K) {
    extern __shared__ _Float16 lds[];  // 2 x (A 4096 | B 8192) elems = 48KB
    const int tid = threadIdx.x;
    const int lane = tid & 63;
    const int wave = tid >> 6;
    const int wm = wave >> 1;  // 0..1 (128 m-rows each)
    const int wn = wave & 1;   // 0..1 (64 n-cols each)
    const int quad = lane >> 4;
    const int r16 = lane & 15;
    const int wm8 = wm * 8;
    const int lrb = lane * 8;  // fragment lane offset (elts), fully linear

    int mt, nt;
    tile_map(blockIdx.x, M >> 8, N >> 7, mt, nt);
    const int m0 = mt * 256;
    const int n0 = nt * 128;

    const int KC = K >> 5;   // 32-k chunks (= K-tiles, BK=32)
    const int KC8 = K >> 3;  // 8-k blocks per activation m-block row
    const int NT = KC;
    const int m016 = m0 >> 4;
    const int nt2 = nt * 2;

    // one stage op = 256 threads x 16B = 4KB, lane-linear into LDS
    auto stageA = [&](int g, int kt, _Float16* pa) {
        gl16(WF + ((size_t)(nt2 + g) * KC + kt) * 2048 + tid * 8,
             pa + g * 2048 + tid * 8);
    };
    auto stageB = [&](int mb, int kt, _Float16* pb) {
        gl16(Xb + ((size_t)(m016 + mb + (tid >> 6)) * KC8 + (size_t)kt * 4) * 128 +
                 (tid & 63) * 8,
             pb + mb * 512 + tid * 8);
    };
    // 4 B-frags (m-blocks mb..mb+3): contiguous 1KB wave sweeps
    auto loadB4 = [&](const _Float16* pB, int mb, v8h (&b)[4]) {
#pragma unroll
        for (int j = 0; j < 4; ++j)
            b[j] = *(const v8h*)(pB + (mb + j) * 512 + lrb);
    };

    v4f acc[8][4];
#pragma unroll
    for (int i = 0; i < 8; ++i)
#pragma unroll
        for (int j = 0; j < 4; ++j) acc[i][j] = (v4f)0.f;

    // ---- prologue: stage tile 0 into buf0, wait, one barrier ----
    {
        _Float16* A0 = lds;
        _Float16* B0 = lds + 4096;
        stageB(0, 0, B0); stageB(4, 0, B0); stageB(8, 0, B0); stageB(12, 0, B0);
        stageA(0, 0, A0); stageA(1, 0, A0);
        asm volatile("s_waitcnt vmcnt(0)" ::: "memory");
        __builtin_amdgcn_s_barrier();
    }

#pragma unroll 2
    for (int kt = 0; kt < NT; ++kt) {
        _Float16* pAc = lds + (kt & 1) * 12288;
        _Float16* pBc = pAc + 4096;
        _Float16* pAn = lds + ((kt + 1) & 1) * 12288;
        _Float16* pBn = pAn + 4096;
        const bool pre = (kt + 1 < NT);
        const int kn = kt + 1;

        // ---- reads for this tile: A frags + first B quad ----
        v8h af[4];
#pragma unroll
        for (int i = 0; i < 4; ++i)
            af[i] = *(const v8h*)(pAc + wn * 2048 + i * 512 + lrb);
        v8h bA[4], bB[4];
        loadB4(pBc, wm8 + 0, bA);

        // ---- issue next-tile staging (lands in other buffer, async) ----
        if (pre) {
            stageB(0, kn, pBn); stageB(4, kn, pBn);
            stageB(8, kn, pBn); stageB(12, kn, pBn);
            stageA(0, kn, pAn); stageA(1, kn, pAn);
        }

        loadB4(pBc, wm8 + 4, bB);

        __builtin_amdgcn_s_setprio(1);
        mfma16<0>(acc, af, bA);
        __builtin_amdgcn_s_setprio(0);
        __builtin_amdgcn_s_setprio(1);
        mfma16<4>(acc, af, bB);
        __builtin_amdgcn_s_setprio(0);

        // ---- tile boundary: the ONLY sync per K-tile ----
        if (kt != NT - 1) {
            // own DMA share of tile t+1 done (ds_reads consumed by MFMAs)
            asm volatile("s_waitcnt vmcnt(0)" ::: "memory");
            __builtin_amdgcn_s_barrier();
        }
    }

    // ---- epilogue: lane holds n = nb+ni*16+quad*4+i, m = mb+mi*16+r16 ----
    const int nb = n0 + wn * 64;
    v4f bv[4];
#pragma unroll
    for (int ni = 0; ni < 4; ++ni)
        bv[ni] = *(const v4f*)&bias[nb + ni * 16 + quad * 4];

    if constexpr (DOT == 0) {
        const int NC8 = N >> 3;
#pragma unroll
        for (int ni = 0; ni < 4; ++ni) {
            const int nblk = ((nb + ni * 16) >> 3) + (quad >> 1);
#pragma unroll
            for (int mi = 0; mi < 8; ++mi) {
                v4h hv;
#pragma unroll
                for (int i = 0; i < 4; ++i)
                    hv[i] = (_Float16)fmaxf(acc[mi][ni][i] + bv[ni][i], 0.f);
                const size_t mblk = (size_t)((m0 + wm * 128 + mi * 16) >> 4);
                _Float16* dst =
                    Cb + (mblk * NC8 + nblk) * 128 + r16 * 8 + (quad & 1) * 4;
                *(v4h*)dst = hv;
            }
        }
    } else {
        v4h wv[4];
#pragma unroll
        for (int ni = 0; ni < 4; ++ni)
            wv[ni] = *(const v4h*)&w3[nb + ni * 16 + quad * 4];
#pragma unroll
        for (int mi = 0; mi < 8; ++mi) {
            float t = 0.f;
#pragma unroll
            for (int ni = 0; ni < 4; ++ni)
#pragma unroll
                for (int i = 0; i < 4; ++i) {
                    float v = fmaxf(acc[mi][ni][i] + bv[ni][i], 0.f);
                    t = fmaf(v, (float)wv[ni][i], t);
                }
            t += __shfl_xor(t, 16);
            t += __shfl_xor(t, 32);
            if (quad == 0) {
                int row = m0 + wm * 128 + mi * 16 + r16;
                atomicAdd(&net[row], t);
            }
        }
    }
}

// ---------------------------------------------------------------------------
// scan: y_t = a*y_{t-1} + b*c1_t + (net_t + b3) ; out = [y0; ys]
// ---------------------------------------------------------------------------
__global__ void scan_kernel(const float* __restrict__ net,
                            const float* __restrict__ c1,
                            const float* __restrict__ u,
                            const float* __restrict__ pa,
                            const float* __restrict__ pb,
                            const float* __restrict__ pb3,
                            float* __restrict__ out) {
    const int bidx = threadIdx.x;  // 0..255
    const float a = pa[0];
    const float b = pb[0];
    const float b3 = pb3[0];
    float y = u[(size_t)bidx * F_DIM];  // u[0, b, 0]
    out[bidx] = y;
#pragma unroll 8
    for (int t = 0; t < T_DIM; ++t) {
        float z = fmaf(b, c1[t * B_DIM + bidx], net[t * B_DIM + bidx] + b3);
        y = fmaf(a, y, z);
        out[(t + 1) * B_DIM + bidx] = y;
    }
}

// ---------------------------------------------------------------------------
extern "C" void kernel_launch(void* const* d_in, const int* in_sizes, int n_in,
                              void* d_out, int out_size, void* d_ws, size_t ws_size,
                              hipStream_t stream) {
    const float* u = (const float*)d_in[0];
    const float* pa = (const float*)d_in[1];
    const float* pb = (const float*)d_in[2];
    const float* W0 = (const float*)d_in[3];
    const float* b0 = (const float*)d_in[4];
    const float* W1 = (const float*)d_in[5];
    const float* b1 = (const float*)d_in[6];
    const float* W2 = (const float*)d_in[7];
    const float* b2 = (const float*)d_in[8];
    const float* W3 = (const float*)d_in[9];
    const float* b3 = (const float*)d_in[10];
    float* out = (float*)d_out;

    char* ws = (char*)d_ws;
    size_t off = 0;
    auto alloc = [&](size_t bytes) -> void* {
        void* p = ws + off;
        off += (bytes + 255) & ~(size_t)255;
        return p;
    };

    // ---- fixed residents (~5.8 MB) ----
    float* net = (float*)alloc((size_t)M_ROWS * 4);
    float* c1 = (float*)alloc((size_t)M_ROWS * 4);
    _Float16* W0F = (_Float16*)alloc((size_t)IN_DIM * H_DIM * 2);
    _Float16* W1F = (_Float16*)alloc((size_t)H_DIM * H_DIM * 2);
    _Float16* W2F = (_Float16*)alloc((size_t)H_DIM * H_DIM * 2);
    _Float16* W3h = (_Float16*)alloc((size_t)H_DIM * 2);

    // ---- chunk rows: multiple of 2048 (256-tile + XCD swizzle path) ----
    const size_t per_row = 512 + 2048 + 2048;
    size_t avail = (ws_size > off + 65536) ? (ws_size - off - 65536) : 0;
    long Rl = (long)(avail / per_row);
    Rl = (Rl / 2048) * 2048;
    if (Rl < 2048) Rl = 2048;
    if (Rl > M_ROWS) Rl = M_ROWS;
    const int R = (int)Rl;

    _Float16* Xc = (_Float16*)alloc((size_t)R * IN_DIM * 2);
    _Float16* HAc = (_Float16*)alloc((size_t)R * H_DIM * 2);
    _Float16* HBc = (_Float16*)alloc((size_t)R * H_DIM * 2);

    // ---- weights once per call (fragment-major) ----
    wt_frag_kernel<<<(IN_DIM / 32) * (H_DIM / 64), 256, 0, stream>>>(W0, W0F,
                                                                     IN_DIM, H_DIM);
    wt_frag_kernel<<<(H_DIM / 32) * (H_DIM / 64), 256, 0, stream>>>(W1, W1F,
                                                                    H_DIM, H_DIM);
    wt_frag_kernel<<<(H_DIM / 32) * (H_DIM / 64), 256, 0, stream>>>(W2, W2F,
                                                                    H_DIM, H_DIM);
    wt_vec_kernel<<<4, 256, 0, stream>>>(W3, W3h, H_DIM);
    zero_kernel<<<M_ROWS / 256, 256, 0, stream>>>(net, M_ROWS);

    // ---- chunked MLP pipeline ----
    const size_t lds_bytes = 49152;  // 2 x (A 8KB + B 16KB)
    for (int r0 = 0; r0 < M_ROWS; r0 += R) {
        int Mc = M_ROWS - r0;
        if (Mc > R) Mc = R;

        int pgrid = (Mc * 32 + 255) / 256;
        if (pgrid > 2048) pgrid = 2048;
        prep_x_kernel<<<pgrid, 256, 0, stream>>>(u + (size_t)r0 * F_DIM, Xc, Mc);
        prep_c1_kernel<<<(Mc + 255) / 256, 256, 0, stream>>>(
            u + (size_t)r0 * F_DIM, c1 + r0, Mc);

        dim3 blk(256);
        dim3 grd((Mc / 256) * (H_DIM / 128));  // 1D, swizzled in-kernel
        gemm256<0><<<grd, blk, lds_bytes, stream>>>(Xc, W0F, b0, nullptr, HAc,
                                                    nullptr, Mc, H_DIM, IN_DIM);
        gemm256<0><<<grd, blk, lds_bytes, stream>>>(HAc, W1F, b1, nullptr, HBc,
                                                    nullptr, Mc, H_DIM, H_DIM);
        gemm256<1><<<grd, blk, lds_bytes, stream>>>(HBc, W2F, b2, W3h, nullptr,
                                                    net + r0, Mc, H_DIM, H_DIM);
    }

    // ---- scan ----
    scan_kernel<<<1, 256, 0, stream>>>(net, c1, u, pa, pb, b3, out);
}

// Round 5
// 917.828 us; speedup vs baseline: 1.1160x; 1.0095x over previous
//
#include <hip/hip_runtime.h>
#include <hip/hip_fp16.h>

typedef _Float16 v8h __attribute__((ext_vector_type(8)));
typedef _Float16 v4h __attribute__((ext_vector_type(4)));
typedef float v4f __attribute__((ext_vector_type(4)));

#define T_DIM 512
#define B_DIM 256
#define F_DIM 258
#define IN_DIM 256
#define H_DIM 1024
#define M_ROWS (T_DIM * B_DIM) /* 131072 */

// XCD-aware tile map: blocks on one XCD share an m-panel across all nt
__device__ __forceinline__ void tile_map(int b, int nM, int nN, int& mt, int& nt) {
    if ((nM & 7) == 0) {
        int xcd = b & 7;
        int l = b >> 3;
        int mpx = nM >> 3;
        int lm = l / nN;
        mt = xcd * mpx + lm;
        nt = l - lm * nN;
    } else {
        int lm = b / nN;
        mt = lm;
        nt = b - lm * nN;
    }
}

// async global->LDS, 16B per lane, lane-linear LDS destination
__device__ __forceinline__ void gl16(const _Float16* g, _Float16* l) {
    __builtin_amdgcn_global_load_lds(
        (const __attribute__((address_space(1))) unsigned int*)g,
        (__attribute__((address_space(3))) unsigned int*)l, 16, 0, 0);
}

// ---------------------------------------------------------------------------
// Activations live in blocked "bk8" layout: X[m][k] at
//   ((m>>4)*(K>>3) + (k>>3))*128 + (m&15)*8 + (k&7)
// -> any B-fragment is one coalesced 16B/lane load; ds_read_b128 of a
//    fragment is a contiguous 1KB wave sweep: zero bank conflicts, and
//    global_load_lds's lane-linear LDS dest maps 1:1 onto the layout.
// ---------------------------------------------------------------------------

// prep: u (Mc,258) fp32 -> X bk8 fp16, vectorized (v8h stores, linear in X)
__global__ void prep_x_kernel(const float* __restrict__ u,
                              _Float16* __restrict__ X, int nrows) {
    int i = blockIdx.x * blockDim.x + threadIdx.x;
    int total = nrows * 32;
    int stride = gridDim.x * blockDim.x;
    for (; i < total; i += stride) {
        int r = ((i >> 9) << 4) + (i & 15);
        int kb = (i >> 4) & 31;
        const float* s = u + (size_t)r * 258 + 2 + kb * 8;
        _Float16 h[8];
#pragma unroll
        for (int j = 0; j < 8; ++j) h[j] = (_Float16)s[j];
        *(v8h*)(X + ((size_t)(r >> 4) * 32 + kb) * 128 + (r & 15) * 8) =
            *(v8h*)h;
    }
}

__global__ void prep_c1_kernel(const float* __restrict__ u,
                               float* __restrict__ c1, int nrows) {
    int r = blockIdx.x * blockDim.x + threadIdx.x;
    if (r < nrows) c1[r] = u[(size_t)r * 258 + 1];
}

// ---------------------------------------------------------------------------
// weight -> fragment-major fp16. W (K x N fp32).
// Frag f=(g*KC+kc)*4+i holds n = g*64+i*16+(l&15), k = kc*32+(l>>4)*8+j.
// ---------------------------------------------------------------------------
__global__ void wt_frag_kernel(const float* __restrict__ W,
                               _Float16* __restrict__ BF, int K, int N) {
    int idx = blockIdx.x * blockDim.x + threadIdx.x;
    int total = (N >> 6) * (K >> 5) * 4 * 64;
    if (idx >= total) return;
    int l = idx & 63;
    int f = idx >> 6;
    int i = f & 3;
    int gk = f >> 2;
    int KC = K >> 5;
    int g = gk / KC, kc = gk - g * KC;
    int col = g * 64 + i * 16 + (l & 15);
    int krow = kc * 32 + (l >> 4) * 8;
    _Float16 tmp[8];
#pragma unroll
    for (int j = 0; j < 8; ++j) tmp[j] = (_Float16)W[(size_t)(krow + j) * N + col];
    *(v8h*)&BF[(size_t)idx * 8] = *(v8h*)tmp;
}

__global__ void wt_vec_kernel(const float* __restrict__ W,
                              _Float16* __restrict__ Wh, int K) {
    int i = blockIdx.x * blockDim.x + threadIdx.x;
    if (i < K) Wh[i] = (_Float16)W[i];
}

__global__ void zero_kernel(float* __restrict__ p, int n) {
    int i = blockIdx.x * blockDim.x + threadIdx.x;
    if (i < n) p[i] = 0.f;
}

// ---------------------------------------------------------------------------
// 256x256 LDS-staged GEMM, 8 waves (2M x 4N), BK=64, double-buffered 128KB
// LDS, one barrier per K-tile. Inner schedule (m201-style hold/stream):
// hold ALL B fragments (16 x v8h = 64 VGPR) for the tile, STREAM A at
// 2 ds_reads per ni-phase -> read-dependency depth before each MFMA
// cluster is <=3 (vs 12 in the R2 mi-phase form), killing the per-tile
// cold-start convoy that pinned MfmaUtil at ~43%.
// ---------------------------------------------------------------------------
template <int DOT>
__global__ __launch_bounds__(512, 2)
void gemm256(const _Float16* __restrict__ Xb, const _Float16* __restrict__ WF,
             const float* __restrict__ bias, const _Float16* __restrict__ w3,
             _Float16* __restrict__ Cb, float* __restrict__ net,
             int M, int N, int K) {
    extern __shared__ _Float16 lds[];  // [buf0: A 16384 | B 16384][buf1: A | B]
    const int tid = threadIdx.x;
    const int lane = tid & 63;
    const int wave = tid >> 6;
    const int wm = wave >> 2;  // 0..1 (128 m-rows each)
    const int wn = wave & 3;   // 0..3 (64 n-cols each)
    const int quad = lane >> 4;
    const int r16 = lane & 15;
    const int wm8 = wm * 8;
    const int lrb = lane * 8;  // fragment lane offset (elts), fully linear

    int mt, nt;
    tile_map(blockIdx.x, M >> 8, N >> 8, mt, nt);
    const int m0 = mt * 256;
    const int n0 = nt * 256;

    const int KC = K >> 5;   // 32-k chunks per weight group
    const int KC8 = K >> 3;  // 8-k blocks per activation m-block row
    const int NT = K >> 6;   // number of 64-k tiles
    const int m016 = m0 >> 4;
    const int nt4 = nt * 4;

    // one stage op = 512 threads x 16B = 8KB, lane-linear into LDS
    auto stageA = [&](int g, int kt, _Float16* pa) {
        gl16(WF + ((size_t)(nt4 + g) * KC + (size_t)kt * 2) * 2048 + tid * 8,
             pa + g * 4096 + tid * 8);
    };
    auto stageB = [&](int mb, int kt, _Float16* pb) {
        gl16(Xb + ((size_t)(m016 + mb + (tid >> 7)) * KC8 + (size_t)kt * 8) * 128 +
                 (tid & 127) * 8,
             pb + mb * 1024 + tid * 8);
    };

    v4f acc[8][4];
#pragma unroll
    for (int i = 0; i < 8; ++i)
#pragma unroll
        for (int j = 0; j < 4; ++j) acc[i][j] = (v4f)0.f;

    // ---- prologue: stage tile 0 into buf0, wait, one barrier ----
    {
        _Float16* A0 = lds;
        _Float16* B0 = lds + 16384;
        stageB(0, 0, B0); stageB(4, 0, B0); stageB(8, 0, B0); stageB(12, 0, B0);
        stageA(0, 0, A0); stageA(1, 0, A0); stageA(2, 0, A0); stageA(3, 0, A0);
        asm volatile("s_waitcnt vmcnt(0)" ::: "memory");
        __builtin_amdgcn_s_barrier();
    }

#pragma unroll 2
    for (int kt = 0; kt < NT; ++kt) {
        _Float16* pAc = lds + (kt & 1) * 32768;
        _Float16* pBc = pAc + 16384;
        _Float16* pAn = lds + ((kt + 1) & 1) * 32768;
        _Float16* pBn = pAn + 16384;
        const bool pre = (kt + 1 < NT);
        const int kn = kt + 1;
        const _Float16* pAw = pAc + wn * 4096;  // this wave's 64-col A group

        // ---- issue: af(ni=0) first (shallow dep), then the whole B tile ----
        v8h afA[2], afB[2];
        afA[0] = *(const v8h*)(pAw + lrb);           // ni=0, k 0..31
        afA[1] = *(const v8h*)(pAw + 2048 + lrb);    // ni=0, k 32..63
        v8h bf[8][2];
#pragma unroll
        for (int mi = 0; mi < 8; ++mi) {
            bf[mi][0] = *(const v8h*)(pBc + (wm8 + mi) * 1024 + lrb);
            bf[mi][1] = *(const v8h*)(pBc + (wm8 + mi) * 1024 + 512 + lrb);
        }

        // ---- issue next-tile staging (lands in other buffer, async) ----
        if (pre) {
            stageB(0, kn, pBn); stageB(4, kn, pBn);
            stageB(8, kn, pBn); stageB(12, kn, pBn);
            stageA(0, kn, pAn); stageA(1, kn, pAn);
            stageA(2, kn, pAn); stageA(3, kn, pAn);
        }

        // ---- ni-phases: stream A (2 reads/phase), B held in regs ----
        // ni = 0 (prefetch ni=1)
        afB[0] = *(const v8h*)(pAw + 512 + lrb);
        afB[1] = *(const v8h*)(pAw + 2560 + lrb);
        __builtin_amdgcn_s_setprio(1);
#pragma unroll
        for (int mi = 0; mi < 8; ++mi) {
            acc[mi][0] = __builtin_amdgcn_mfma_f32_16x16x32_f16(
                afA[0], bf[mi][0], acc[mi][0], 0, 0, 0);
            acc[mi][0] = __builtin_amdgcn_mfma_f32_16x16x32_f16(
                afA[1], bf[mi][1], acc[mi][0], 0, 0, 0);
        }
        __builtin_amdgcn_s_setprio(0);

        // ni = 1 (prefetch ni=2)
        afA[0] = *(const v8h*)(pAw + 1024 + lrb);
        afA[1] = *(const v8h*)(pAw + 3072 + lrb);
        __builtin_amdgcn_s_setprio(1);
#pragma unroll
        for (int mi = 0; mi < 8; ++mi) {
            acc[mi][1] = __builtin_amdgcn_mfma_f32_16x16x32_f16(
                afB[0], bf[mi][0], acc[mi][1], 0, 0, 0);
            acc[mi][1] = __builtin_amdgcn_mfma_f32_16x16x32_f16(
                afB[1], bf[mi][1], acc[mi][1], 0, 0, 0);
        }
        __builtin_amdgcn_s_setprio(0);

        // ni = 2 (prefetch ni=3)
        afB[0] = *(const v8h*)(pAw + 1536 + lrb);
        afB[1] = *(const v8h*)(pAw + 3584 + lrb);
        __builtin_amdgcn_s_setprio(1);
#pragma unroll
        for (int mi = 0; mi < 8; ++mi) {
            acc[mi][2] = __builtin_amdgcn_mfma_f32_16x16x32_f16(
                afA[0], bf[mi][0], acc[mi][2], 0, 0, 0);
            acc[mi][2] = __builtin_amdgcn_mfma_f32_16x16x32_f16(
                afA[1], bf[mi][1], acc[mi][2], 0, 0, 0);
        }
        __builtin_amdgcn_s_setprio(0);

        // ni = 3
        __builtin_amdgcn_s_setprio(1);
#pragma unroll
        for (int mi = 0; mi < 8; ++mi) {
            acc[mi][3] = __builtin_amdgcn_mfma_f32_16x16x32_f16(
                afB[0], bf[mi][0], acc[mi][3], 0, 0, 0);
            acc[mi][3] = __builtin_amdgcn_mfma_f32_16x16x32_f16(
                afB[1], bf[mi][1], acc[mi][3], 0, 0, 0);
        }
        __builtin_amdgcn_s_setprio(0);

        // ---- tile boundary: the ONLY sync per K-tile ----
        if (kt != NT - 1) {
            // own LDS reads of buf[cur] retired (consumed by MFMAs above)
            asm volatile("s_waitcnt lgkmcnt(0)" ::: "memory");
            // own DMA share of tile t+1 landed
            asm volatile("s_waitcnt vmcnt(0)" ::: "memory");
            // all waves: buf[cur^1] fully written, buf[cur] free for t+2 DMA
            __builtin_amdgcn_s_barrier();
        }
    }

    // ---- epilogue: lane holds n = nb+ni*16+quad*4+i, m = mb+mi*16+r16 ----
    const int nb = n0 + wn * 64;
    v4f bv[4];
#pragma unroll
    for (int ni = 0; ni < 4; ++ni)
        bv[ni] = *(const v4f*)&bias[nb + ni * 16 + quad * 4];

    if constexpr (DOT == 0) {
        const int NC8 = N >> 3;
#pragma unroll
        for (int ni = 0; ni < 4; ++ni) {
            const int nblk = ((nb + ni * 16) >> 3) + (quad >> 1);
#pragma unroll
            for (int mi = 0; mi < 8; ++mi) {
                v4h hv;
#pragma unroll
                for (int i = 0; i < 4; ++i)
                    hv[i] = (_Float16)fmaxf(acc[mi][ni][i] + bv[ni][i], 0.f);
                const size_t mblk = (size_t)((m0 + wm * 128 + mi * 16) >> 4);
                _Float16* dst =
                    Cb + (mblk * NC8 + nblk) * 128 + r16 * 8 + (quad & 1) * 4;
                *(v4h*)dst = hv;
            }
        }
    } else {
        v4h wv[4];
#pragma unroll
        for (int ni = 0; ni < 4; ++ni)
            wv[ni] = *(const v4h*)&w3[nb + ni * 16 + quad * 4];
#pragma unroll
        for (int mi = 0; mi < 8; ++mi) {
            float t = 0.f;
#pragma unroll
            for (int ni = 0; ni < 4; ++ni)
#pragma unroll
                for (int i = 0; i < 4; ++i) {
                    float v = fmaxf(acc[mi][ni][i] + bv[ni][i], 0.f);
                    t = fmaf(v, (float)wv[ni][i], t);
                }
            t += __shfl_xor(t, 16);
            t += __shfl_xor(t, 32);
            if (quad == 0) {
                int row = m0 + wm * 128 + mi * 16 + r16;
                atomicAdd(&net[row], t);
            }
        }
    }
}

// ---------------------------------------------------------------------------
// scan: y_t = a*y_{t-1} + b*c1_t + (net_t + b3) ; out = [y0; ys]
// ---------------------------------------------------------------------------
__global__ void scan_kernel(const float* __restrict__ net,
                            const float* __restrict__ c1,
                            const float* __restrict__ u,
                            const float* __restrict__ pa,
                            const float* __restrict__ pb,
                            const float* __restrict__ pb3,
                            float* __restrict__ out) {
    const int bidx = threadIdx.x;  // 0..255
    const float a = pa[0];
    const float b = pb[0];
    const float b3 = pb3[0];
    float y = u[(size_t)bidx * F_DIM];  // u[0, b, 0]
    out[bidx] = y;
#pragma unroll 8
    for (int t = 0; t < T_DIM; ++t) {
        float z = fmaf(b, c1[t * B_DIM + bidx], net[t * B_DIM + bidx] + b3);
        y = fmaf(a, y, z);
        out[(t + 1) * B_DIM + bidx] = y;
    }
}

// ---------------------------------------------------------------------------
extern "C" void kernel_launch(void* const* d_in, const int* in_sizes, int n_in,
                              void* d_out, int out_size, void* d_ws, size_t ws_size,
                              hipStream_t stream) {
    const float* u = (const float*)d_in[0];
    const float* pa = (const float*)d_in[1];
    const float* pb = (const float*)d_in[2];
    const float* W0 = (const float*)d_in[3];
    const float* b0 = (const float*)d_in[4];
    const float* W1 = (const float*)d_in[5];
    const float* b1 = (const float*)d_in[6];
    const float* W2 = (const float*)d_in[7];
    const float* b2 = (const float*)d_in[8];
    const float* W3 = (const float*)d_in[9];
    const float* b3 = (const float*)d_in[10];
    float* out = (float*)d_out;

    char* ws = (char*)d_ws;
    size_t off = 0;
    auto alloc = [&](size_t bytes) -> void* {
        void* p = ws + off;
        off += (bytes + 255) & ~(size_t)255;
        return p;
    };

    // ---- fixed residents (~5.8 MB) ----
    float* net = (float*)alloc((size_t)M_ROWS * 4);
    float* c1 = (float*)alloc((size_t)M_ROWS * 4);
    _Float16* W0F = (_Float16*)alloc((size_t)IN_DIM * H_DIM * 2);
    _Float16* W1F = (_Float16*)alloc((size_t)H_DIM * H_DIM * 2);
    _Float16* W2F = (_Float16*)alloc((size_t)H_DIM * H_DIM * 2);
    _Float16* W3h = (_Float16*)alloc((size_t)H_DIM * 2);

    // ---- chunk rows: multiple of 2048 (256-tile + XCD swizzle path) ----
    const size_t per_row = 512 + 2048 + 2048;
    size_t avail = (ws_size > off + 65536) ? (ws_size - off - 65536) : 0;
    long Rl = (long)(avail / per_row);
    Rl = (Rl / 2048) * 2048;
    if (Rl < 2048) Rl = 2048;
    if (Rl > M_ROWS) Rl = M_ROWS;
    const int R = (int)Rl;

    _Float16* Xc = (_Float16*)alloc((size_t)R * IN_DIM * 2);
    _Float16* HAc = (_Float16*)alloc((size_t)R * H_DIM * 2);
    _Float16* HBc = (_Float16*)alloc((size_t)R * H_DIM * 2);

    // ---- weights once per call (fragment-major) ----
    wt_frag_kernel<<<(IN_DIM / 32) * (H_DIM / 64), 256, 0, stream>>>(W0, W0F,
                                                                     IN_DIM, H_DIM);
    wt_frag_kernel<<<(H_DIM / 32) * (H_DIM / 64), 256, 0, stream>>>(W1, W1F,
                                                                    H_DIM, H_DIM);
    wt_frag_kernel<<<(H_DIM / 32) * (H_DIM / 64), 256, 0, stream>>>(W2, W2F,
                                                                    H_DIM, H_DIM);
    wt_vec_kernel<<<4, 256, 0, stream>>>(W3, W3h, H_DIM);
    zero_kernel<<<M_ROWS / 256, 256, 0, stream>>>(net, M_ROWS);

    // ---- chunked MLP pipeline ----
    const size_t lds_bytes = 131072;  // 2 buf x (A 32KB + B 32KB)
    for (int r0 = 0; r0 < M_ROWS; r0 += R) {
        int Mc = M_ROWS - r0;
        if (Mc > R) Mc = R;

        int pgrid = (Mc * 32 + 255) / 256;
        if (pgrid > 2048) pgrid = 2048;
        prep_x_kernel<<<pgrid, 256, 0, stream>>>(u + (size_t)r0 * F_DIM, Xc, Mc);
        prep_c1_kernel<<<(Mc + 255) / 256, 256, 0, stream>>>(
            u + (size_t)r0 * F_DIM, c1 + r0, Mc);

        dim3 blk(512);
        dim3 grd((Mc / 256) * (H_DIM / 256));  // 1D, swizzled in-kernel
        gemm256<0><<<grd, blk, lds_bytes, stream>>>(Xc, W0F, b0, nullptr, HAc,
                                                    nullptr, Mc, H_DIM, IN_DIM);
        gemm256<0><<<grd, blk, lds_bytes, stream>>>(HAc, W1F, b1, nullptr, HBc,
                                                    nullptr, Mc, H_DIM, H_DIM);
        gemm256<1><<<grd, blk, lds_bytes, stream>>>(HBc, W2F, b2, W3h, nullptr,
                                                    net + r0, Mc, H_DIM, H_DIM);
    }

    // ---- scan ----
    scan_kernel<<<1, 256, 0, stream>>>(net, c1, u, pa, pb, b3, out);
}